// Round 5
// baseline (160.502 us; speedup 1.0000x reference)
//
#include <hip/hip_runtime.h>
#include <math.h>

#define NB 8
#define NN 8192
#define ND 1024
#define NH 256
#define NC 2
#define M_ALL (NB * NN)   // 65536 rows
#define BK 32
#define NT (ND / BK)      // 32 K-steps
#define AROW 40           // ushorts per LDS row (80 B stride: 2-way max bank aliasing)

typedef __attribute__((ext_vector_type(8))) short bf16x8;
typedef __attribute__((ext_vector_type(4))) float f32x4;

// barrier WITHOUT the compiler's vmcnt(0) drain: LDS ordering only.
#define BARRIER_LGKM() asm volatile("s_waitcnt lgkmcnt(0)\n\ts_barrier" ::: "memory")

__device__ inline unsigned short f2bf(float f) {   // RNE float -> bf16 bits
    unsigned int u = __builtin_bit_cast(unsigned int, f);
    u += 0x7FFFu + ((u >> 16) & 1u);
    return (unsigned short)(u >> 16);
}
__device__ inline float bf2f(unsigned short s) {
    unsigned int u = ((unsigned int)s) << 16;
    return __builtin_bit_cast(float, u);
}
__device__ inline unsigned int pk_bf16(float a, float b) {  // low=a, high=b
    return (unsigned int)f2bf(a) | ((unsigned int)f2bf(b) << 16);
}

__device__ inline float wave_reduce_sum(float v) {
#pragma unroll
    for (int off = 32; off > 0; off >>= 1) v += __shfl_down(v, off, 64);
    return v;
}
__device__ inline float wave_reduce_max(float v) {
#pragma unroll
    for (int off = 32; off > 0; off >>= 1) v = fmaxf(v, __shfl_down(v, off, 64));
    return v;
}

// ---------------------------------------------------------------------------
// Pack Wp into bf16 hi/lo, MFMA-B-fragment-contiguous:
// frag (t = k-step 0..31, f = col-frag 0..15), lane l holds
// B[k = t*32 + (l>>4)*8 + j][col = f*16 + (l&15)], j=0..7 contiguous.
// ---------------------------------------------------------------------------
__global__ void pack_kernel(const float* __restrict__ Wp,
                            unsigned short* __restrict__ hi,
                            unsigned short* __restrict__ lo)
{
    int idx  = blockIdx.x * 256 + threadIdx.x;   // 0..32767
    int lane = idx & 63;
    int f    = (idx >> 6) & 15;
    int t    = idx >> 10;
    int col  = f * 16 + (lane & 15);
    int k0   = t * 32 + (lane >> 4) * 8;
    size_t off = (size_t)idx * 8;
#pragma unroll
    for (int j = 0; j < 8; ++j) {
        float w = Wp[(size_t)(k0 + j) * NH + col];
        unsigned short h = f2bf(w);
        hi[off + j] = h;
        lo[off + j] = f2bf(w - bf2f(h));
    }
}

// ---------------------------------------------------------------------------
// GEMM: h = silu(x @ Wp + bp) stored bf16; fused a = h @ Wa + ba.
// 4 waves, tile 64 x 256, BK=32. x pipeline depth = 2 iterations (rE/rO reg
// buffers) so the dswrite vmcnt wait covers full HBM latency. B (L2) issued
// at iter start; MFMAs split hi-block then lo-block so bl latency hides
// under the hi MFMAs. lgkm-only barriers keep global loads in flight.
// ---------------------------------------------------------------------------
__global__ __launch_bounds__(256, 3)
void gemm_kernel(const float* __restrict__ x,
                 const unsigned short* __restrict__ Bhi,
                 const unsigned short* __restrict__ Blo,
                 const float* __restrict__ bp,
                 const float* __restrict__ Wa,
                 const float* __restrict__ ba,
                 unsigned short* __restrict__ h_out,
                 float* __restrict__ a_out)
{
    __shared__ __align__(16) unsigned short As[2][64 * AROW];  // 2 x 5 KB
    __shared__ float a_red[4][64];

    const int tid  = threadIdx.x;
    const int wave = tid >> 6;
    const int lane = tid & 63;
    const size_t row0 = (size_t)blockIdx.x * 64;

    // staging: thread -> row srow, k-slot slot (8 fp32 = 32 B)
    const int srow = tid >> 2;
    const int slot = tid & 3;
    const float* xp = x + (row0 + srow) * ND + slot * 8;
    unsigned short* const wp0 = &As[0][srow * AROW + slot * 8];
    unsigned short* const wp1 = &As[1][srow * AROW + slot * 8];

    // B frag bases (frag idx = t*16 + wave*4 + n; 512 ushorts per frag)
    const unsigned short* bhp = Bhi + ((size_t)(wave * 4) * 64 + lane) * 8;
    const unsigned short* blp = Blo + ((size_t)(wave * 4) * 64 + lane) * 8;

    float4 gaE, gbE, gaO, gbO;                 // x reg buffers, 2-iter lifetime
    bf16x8 bh[4], bl[4];

    auto loadX = [&](int t, float4& A, float4& B) {
        const float4* p = (const float4*)(xp + t * BK);
        A = p[0]; B = p[1];
    };
    auto loadBH = [&](int t) {
        const unsigned short* base = bhp + (size_t)t * 8192;
#pragma unroll
        for (int n = 0; n < 4; ++n) bh[n] = *(const bf16x8*)(base + n * 512);
    };
    auto loadBL = [&](int t) {
        const unsigned short* base = blp + (size_t)t * 8192;
#pragma unroll
        for (int n = 0; n < 4; ++n) bl[n] = *(const bf16x8*)(base + n * 512);
    };
    auto dswrite = [&](unsigned short* wp, const float4& A, const float4& B) {
        uint4 w;
        w.x = pk_bf16(A.x, A.y);
        w.y = pk_bf16(A.z, A.w);
        w.z = pk_bf16(B.x, B.y);
        w.w = pk_bf16(B.z, B.w);
        *(uint4*)wp = w;
    };

    f32x4 acc[4][4];
#pragma unroll
    for (int m = 0; m < 4; ++m)
#pragma unroll
        for (int n = 0; n < 4; ++n) acc[m][n] = f32x4{0.f, 0.f, 0.f, 0.f};

    auto mfma_phase = [&](int buf) {
        bf16x8 afr[4];
#pragma unroll
        for (int m = 0; m < 4; ++m)
            afr[m] = *(const bf16x8*)&As[buf][(m * 16 + (lane & 15)) * AROW + (lane >> 4) * 8];
#pragma unroll
        for (int n = 0; n < 4; ++n)
#pragma unroll
            for (int m = 0; m < 4; ++m)
                acc[m][n] = __builtin_amdgcn_mfma_f32_16x16x32_bf16(afr[m], bh[n], acc[m][n], 0, 0, 0);
        __builtin_amdgcn_sched_barrier(0);     // keep lo MFMAs after hi (bl latency cover)
#pragma unroll
        for (int n = 0; n < 4; ++n)
#pragma unroll
            for (int m = 0; m < 4; ++m)
                acc[m][n] = __builtin_amdgcn_mfma_f32_16x16x32_bf16(afr[m], bl[n], acc[m][n], 0, 0, 0);
    };

    // prologue: tiles 0,1 -> regs; bh(0); tile0 -> LDS buf0; tile2 -> rE
    loadX(0, gaE, gbE);
    loadX(1, gaO, gbO);
    loadBH(0);
    dswrite(wp0, gaE, gbE);     // waits only the tile-0 loads
    loadX(2, gaE, gbE);
    BARRIER_LGKM();

    for (int tt = 0; tt < NT; tt += 2) {
        const int te = tt, to = tt + 1;
        // ---- even sub-iter te: MFMA reads buf0; stage tile te+1 -> buf1
        dswrite(wp1, gaO, gbO);                        // tile te+1 (loaded 2 iters ago)
        loadBL(te);
        { int txx = te + 3 < NT ? te + 3 : NT - 1; loadX(txx, gaO, gbO); }
        __builtin_amdgcn_sched_barrier(0);
        mfma_phase(0);
        { int tb = to < NT ? to : NT - 1; loadBH(tb); }    // bh for next sub-iter
        BARRIER_LGKM();
        // ---- odd sub-iter to: MFMA reads buf1; stage tile to+1 -> buf0
        dswrite(wp0, gaE, gbE);                        // tile to+1
        loadBL(to);
        { int txx = to + 3 < NT ? to + 3 : NT - 1; loadX(txx, gaE, gbE); }
        __builtin_amdgcn_sched_barrier(0);
        mfma_phase(1);
        { int tb = to + 1 < NT ? to + 1 : NT - 1; loadBH(tb); }
        BARRIER_LGKM();
    }

    // epilogue: bias + SiLU, store h bf16, fused attention logits
    float pa[16];
#pragma unroll
    for (int i = 0; i < 16; ++i) pa[i] = 0.f;

#pragma unroll
    for (int n = 0; n < 4; ++n) {
        int col = wave * 64 + n * 16 + (lane & 15);
        float bpc = bp[col];
        float wac = Wa[col];
#pragma unroll
        for (int m = 0; m < 4; ++m) {
            size_t rowb = row0 + m * 16 + ((lane >> 4) * 4);
#pragma unroll
            for (int j = 0; j < 4; ++j) {
                float v  = acc[m][n][j] + bpc;
                float hh = v / (1.f + __expf(-v));
                h_out[(rowb + j) * NH + col] = f2bf(hh);
                pa[m * 4 + j] = fmaf(hh, wac, pa[m * 4 + j]);
            }
        }
    }
#pragma unroll
    for (int i = 0; i < 16; ++i) {
#pragma unroll
        for (int off = 1; off < 16; off <<= 1)
            pa[i] += __shfl_xor(pa[i], off, 64);
    }
    if ((lane & 15) == 0) {
        int rg = lane >> 4;
#pragma unroll
        for (int m = 0; m < 4; ++m)
#pragma unroll
            for (int j = 0; j < 4; ++j)
                a_red[wave][m * 16 + rg * 4 + j] = pa[m * 4 + j];
    }
    __syncthreads();
    if (tid < 64) {
        float av = a_red[0][tid] + a_red[1][tid] + a_red[2][tid] + a_red[3][tid] + ba[0];
        a_out[row0 + tid] = av;
    }
}

// ---------------------------------------------------------------------------
// Merged softmax: per-bag max + sumexp + write normalized probs p[n]
// (p = 0 beyond len, so downstream needs no length logic). 8 blocks x 1024.
// ---------------------------------------------------------------------------
__global__ __launch_bounds__(1024)
void stats_kernel(const float* __restrict__ a, const int* __restrict__ lengths,
                  float* __restrict__ p)
{
    __shared__ float red[16];
    __shared__ float bcast;
    const int b = blockIdx.x, tid = threadIdx.x;
    const int wid = tid >> 6, lane = tid & 63;
    const int len = lengths[b];
    const float* ab = a + (size_t)b * NN;

    float v[8];
    bool valid[8];
    float m = -3e38f;
#pragma unroll
    for (int i = 0; i < 8; ++i) {
        int n = tid + i * 1024;
        valid[i] = n < len;
        v[i] = valid[i] ? ab[n] : -3e38f;
        m = fmaxf(m, v[i]);
    }
    m = wave_reduce_max(m);
    if (lane == 0) red[wid] = m;
    __syncthreads();
    if (tid < 64) {
        float mm = (lane < 16) ? red[lane] : -3e38f;
        mm = wave_reduce_max(mm);
        if (lane == 0) bcast = mm;
    }
    __syncthreads();
    m = bcast;

    float e[8];
    float s = 0.f;
#pragma unroll
    for (int i = 0; i < 8; ++i) {
        e[i] = valid[i] ? expf(v[i] - m) : 0.f;
        s += e[i];
    }
    s = wave_reduce_sum(s);
    __syncthreads();               // red reuse
    if (lane == 0) red[wid] = s;
    __syncthreads();
    if (tid < 64) {
        float ss = (lane < 16) ? red[lane] : 0.f;
        ss = wave_reduce_sum(ss);
        if (lane == 0) bcast = ss;
    }
    __syncthreads();
    const float inv = 1.f / bcast;
#pragma unroll
    for (int i = 0; i < 8; ++i)
        p[(size_t)b * NN + tid + i * 1024] = e[i] * inv;
}

// ---------------------------------------------------------------------------
// partial pooled: grid (32, NB), 256 thr. thread: sub = tid>>6 (row phase),
// cg = tid&63 (4 cols). 64 rows/thread, ushort4 h loads, p broadcast.
// ---------------------------------------------------------------------------
__global__ __launch_bounds__(256)
void pool_kernel(const unsigned short* __restrict__ h, const float* __restrict__ p,
                 float* __restrict__ part)
{
    const int b = blockIdx.y;
    const int s = blockIdx.x;
    const int sub = threadIdx.x >> 6;
    const int cg  = threadIdx.x & 63;
    const int n0  = s * 256 + sub;

    const unsigned short* hb = h + ((size_t)b * NN + n0) * NH + cg * 4;
    const float* pb = p + (size_t)b * NN + n0;

    float ax = 0.f, ay = 0.f, az = 0.f, aw = 0.f;
#pragma unroll 8
    for (int i = 0; i < 64; ++i) {
        float pv = pb[i * 4];
        ushort4 hv = *(const ushort4*)(hb + (size_t)i * 4 * NH);
        ax = fmaf(pv, bf2f(hv.x), ax);
        ay = fmaf(pv, bf2f(hv.y), ay);
        az = fmaf(pv, bf2f(hv.z), az);
        aw = fmaf(pv, bf2f(hv.w), aw);
    }
    float4 res = {ax, ay, az, aw};
    *(float4*)(part + (((size_t)(b * 32 + s) * 4 + sub) * 64 + cg) * 4) = res;
}

// ---------------------------------------------------------------------------
// pooled = sum of 128 partials; logits = pooled @ Wc + bc
// ---------------------------------------------------------------------------
__global__ void final_kernel(const float* __restrict__ part, const float* __restrict__ Wc,
                             const float* __restrict__ bc, float* __restrict__ out)
{
    __shared__ float red0[4], red1[4];
    const int c = threadIdx.x;
    const float wc0 = Wc[c * NC + 0], wc1 = Wc[c * NC + 1];
    const int wave = threadIdx.x >> 6, lane = threadIdx.x & 63;

    for (int b = 0; b < NB; ++b) {
        float pooled = 0.f;
#pragma unroll 8
        for (int k = 0; k < 128; ++k)
            pooled += part[((size_t)b * 128 + k) * NH + c];
        float l0 = wave_reduce_sum(pooled * wc0);
        float l1 = wave_reduce_sum(pooled * wc1);
        if (lane == 0) { red0[wave] = l0; red1[wave] = l1; }
        __syncthreads();
        if (threadIdx.x == 0) {
            out[b * NC + 0] = red0[0] + red0[1] + red0[2] + red0[3] + bc[0];
            out[b * NC + 1] = red1[0] + red1[1] + red1[2] + red1[3] + bc[1];
        }
        __syncthreads();
    }
}

extern "C" void kernel_launch(void* const* d_in, const int* in_sizes, int n_in,
                              void* d_out, int out_size, void* d_ws, size_t ws_size,
                              hipStream_t stream)
{
    const float* x       = (const float*)d_in[0];
    const int*   lengths = (const int*)d_in[1];
    const float* Wp      = (const float*)d_in[2];
    const float* bp      = (const float*)d_in[3];
    const float* Wa      = (const float*)d_in[4];
    const float* ba      = (const float*)d_in[5];
    const float* Wc      = (const float*)d_in[6];
    const float* bc      = (const float*)d_in[7];
    float* out = (float*)d_out;

    // workspace layout
    unsigned short* whi   = (unsigned short*)d_ws;            // 262144 bf16
    unsigned short* wlo   = whi + 262144;
    unsigned short* h_buf = wlo + 262144;                     // 16.7M bf16 (32 MB)
    float*  a_buf  = (float*)(h_buf + (size_t)M_ALL * NH);    // 65536 f
    float*  p_buf  = a_buf + M_ALL;                           // 65536 f
    float*  part   = p_buf + M_ALL;                           // 8*128*256 f (1 MB)

    pack_kernel<<<128, 256, 0, stream>>>(Wp, whi, wlo);
    gemm_kernel<<<M_ALL / 64, 256, 0, stream>>>(x, whi, wlo, bp, Wa, ba, h_buf, a_buf);
    stats_kernel<<<NB, 1024, 0, stream>>>(a_buf, lengths, p_buf);
    pool_kernel<<<dim3(32, NB), 256, 0, stream>>>(h_buf, p_buf, part);
    final_kernel<<<1, 256, 0, stream>>>(part, Wc, bc, out);
}

// Round 6
// 138.820 us; speedup vs baseline: 1.1562x; 1.1562x over previous
//
#include <hip/hip_runtime.h>
#include <hip/hip_bf16.h>
#include <math.h>

#define NB 8
#define NN 8192
#define ND 1024
#define NH 256
#define NC 2
#define M_ALL (NB * NN)   // 65536 rows
#define BM 256            // block tile rows
#define BKK 64            // K per iteration
#define NT (ND / BKK)     // 16 iterations

typedef __attribute__((ext_vector_type(8))) short bf16x8;
typedef __attribute__((ext_vector_type(4))) float f32x4;

// barrier WITHOUT the compiler's vmcnt(0) drain: LDS ordering only.
#define BARRIER_LGKM() asm volatile("s_waitcnt lgkmcnt(0)\n\ts_barrier" ::: "memory")
// XOR swizzle within a 128-B LDS row: kills same-bank column alignment
#define SWZ(row, off) ((off) ^ (((row) & 7) << 4))

__device__ inline unsigned short f2bf(float f) {   // RNE float -> bf16 bits
    unsigned int u = __builtin_bit_cast(unsigned int, f);
    u += 0x7FFFu + ((u >> 16) & 1u);
    return (unsigned short)(u >> 16);
}
__device__ inline float bf2f(unsigned short s) {
    unsigned int u = ((unsigned int)s) << 16;
    return __builtin_bit_cast(float, u);
}
__device__ inline unsigned int pk_bf16(float a, float b) {  // v_cvt_pk_bf16_f32 path
    __hip_bfloat162 t = __float22bfloat162_rn(float2{a, b});
    unsigned int r;
    __builtin_memcpy(&r, &t, 4);
    return r;
}

__device__ inline float wave_reduce_sum(float v) {
#pragma unroll
    for (int off = 32; off > 0; off >>= 1) v += __shfl_down(v, off, 64);
    return v;
}
__device__ inline float wave_reduce_max(float v) {
#pragma unroll
    for (int off = 32; off > 0; off >>= 1) v = fmaxf(v, __shfl_down(v, off, 64));
    return v;
}

// ---------------------------------------------------------------------------
// Pack Wp into bf16 hi/lo, MFMA-B-fragment-contiguous:
// frag (t = kstep 0..31, f = col-frag 0..15), lane l holds
// B[k = t*32 + (l>>4)*8 + j][col = f*16 + (l&15)], j=0..7 contiguous.
// ---------------------------------------------------------------------------
__global__ void pack_kernel(const float* __restrict__ Wp,
                            unsigned short* __restrict__ hi,
                            unsigned short* __restrict__ lo)
{
    int idx  = blockIdx.x * 256 + threadIdx.x;   // 0..32767
    int lane = idx & 63;
    int f    = (idx >> 6) & 15;
    int t    = idx >> 10;
    int col  = f * 16 + (lane & 15);
    int k0   = t * 32 + (lane >> 4) * 8;
    size_t off = (size_t)idx * 8;
#pragma unroll
    for (int j = 0; j < 8; ++j) {
        float w = Wp[(size_t)(k0 + j) * NH + col];
        unsigned short h = f2bf(w);
        hi[off + j] = h;
        lo[off + j] = f2bf(w - bf2f(h));
    }
}

// ---------------------------------------------------------------------------
// GEMM: h = silu(x @ Wp + bp) stored bf16; fused a = h @ Wa + ba.
// 256x256 tile, 8 waves (2 row-groups x 4 col-groups), BK=64, 16 iters.
// LDS 2 x [256][64] bf16 (64 KB), XOR-swizzled; x staged global->reg->LDS
// with depth-1 prefetch (one iter = ~5000 cyc >> HBM latency).
// One lgkm-only barrier per iter. 256 blocks = 1 per CU, no tail.
// ---------------------------------------------------------------------------
__global__ __launch_bounds__(512, 2)
void gemm_kernel(const float* __restrict__ x,
                 const unsigned short* __restrict__ Bhi,
                 const unsigned short* __restrict__ Blo,
                 const float* __restrict__ bp,
                 const float* __restrict__ Wa,
                 const float* __restrict__ ba,
                 unsigned short* __restrict__ h_out,
                 float* __restrict__ a_out)
{
    __shared__ __align__(16) unsigned short As[2][BM][BKK];   // 64 KB exactly

    const int tid  = threadIdx.x;
    const int wave = tid >> 6;
    const int lane = tid & 63;
    const int wr = wave >> 2;          // 0..1: row group (128 rows)
    const int wc = wave & 3;           // 0..3: col group (64 cols)
    const size_t row0 = (size_t)blockIdx.x * BM;

    // staging: thread -> row srow (0..255), half (32 floats = 64 B bf16)
    const int srow  = tid >> 1;
    const int shalf = tid & 1;
    const float* xp = x + (row0 + srow) * ND + shalf * 32;
    char* const wbase0 = (char*)&As[0][srow][0];
    char* const wbase1 = (char*)&As[1][srow][0];
    int woff[4];
#pragma unroll
    for (int q = 0; q < 4; ++q) woff[q] = SWZ(srow, shalf * 64 + q * 16);

    float4 g[8];   // landing zone for next x tile (32 VGPR)
    auto loadX = [&](int t) {
        const float4* p = (const float4*)(xp + (size_t)t * BKK);
#pragma unroll
        for (int i = 0; i < 8; ++i) g[i] = p[i];
    };
    auto dswrite = [&](char* wb) {
#pragma unroll
        for (int q = 0; q < 4; ++q) {
            uint4 w;
            w.x = pk_bf16(g[2 * q].x,     g[2 * q].y);
            w.y = pk_bf16(g[2 * q].z,     g[2 * q].w);
            w.z = pk_bf16(g[2 * q + 1].x, g[2 * q + 1].y);
            w.w = pk_bf16(g[2 * q + 1].z, g[2 * q + 1].w);
            *(uint4*)(wb + woff[q]) = w;
        }
    };

    f32x4 acc[8][4];
#pragma unroll
    for (int m = 0; m < 8; ++m)
#pragma unroll
        for (int n = 0; n < 4; ++n) acc[m][n] = f32x4{0.f, 0.f, 0.f, 0.f};

    // B frag pointers: frag idx = kstep*16 + (wc*4+n), 512 ushorts per frag
    const unsigned short* bh_it = Bhi + ((size_t)(wc * 4) * 64 + lane) * 8;
    const unsigned short* bl_it = Blo + ((size_t)(wc * 4) * 64 + lane) * 8;

    const int arow_l = lane & 15;
    const int akoff  = (lane >> 4) * 16;   // byte offset of 8-elem k-slot

    auto phase = [&](const unsigned short* bhB, const unsigned short* blB,
                     const char* abase, int ksoff) {
        bf16x8 bh[4], bl[4];
#pragma unroll
        for (int n = 0; n < 4; ++n) {
            bh[n] = *(const bf16x8*)(bhB + n * 512);
            bl[n] = *(const bf16x8*)(blB + n * 512);
        }
#pragma unroll
        for (int m = 0; m < 8; ++m) {
            int arow = wr * 128 + m * 16 + arow_l;
            bf16x8 a = *(const bf16x8*)(abase + arow * 128 + SWZ(arow, ksoff + akoff));
#pragma unroll
            for (int n = 0; n < 4; ++n) {
                acc[m][n] = __builtin_amdgcn_mfma_f32_16x16x32_bf16(a, bh[n], acc[m][n], 0, 0, 0);
                acc[m][n] = __builtin_amdgcn_mfma_f32_16x16x32_bf16(a, bl[n], acc[m][n], 0, 0, 0);
            }
        }
    };

    // prologue: tile0 -> LDS buf0; tile1 -> regs
    loadX(0);
    dswrite(wbase0);
    loadX(1);
    BARRIER_LGKM();

    for (int t = 0; t < NT; ++t) {
        if (t < NT - 1) dswrite((t & 1) ? wbase0 : wbase1);  // stage tile t+1
        if (t < NT - 2) loadX(t + 2);                        // prefetch tile t+2
        const char* abase = (const char*)&As[t & 1][0][0];
        phase(bh_it,        bl_it,        abase, 0);         // kstep 2t
        phase(bh_it + 8192, bl_it + 8192, abase, 64);        // kstep 2t+1
        bh_it += 16384; bl_it += 16384;
        BARRIER_LGKM();
    }

    // epilogue: bias + SiLU, h store (bf16), fused attention logits
    float pa[32];
#pragma unroll
    for (int i = 0; i < 32; ++i) pa[i] = 0.f;

#pragma unroll
    for (int n = 0; n < 4; ++n) {
        int col = wc * 64 + n * 16 + (lane & 15);
        float bpc = bp[col];
        float wac = Wa[col];
#pragma unroll
        for (int m = 0; m < 8; ++m) {
            size_t rowb = row0 + wr * 128 + m * 16 + ((lane >> 4) * 4);
#pragma unroll
            for (int j = 0; j < 4; ++j) {
                float v  = acc[m][n][j] + bpc;
                float hh = v / (1.f + __expf(-v));
                h_out[(rowb + j) * NH + col] = f2bf(hh);
                pa[m * 4 + j] = fmaf(hh, wac, pa[m * 4 + j]);
            }
        }
    }
    // reduce pa over the 16 lanes sharing each row
#pragma unroll
    for (int i = 0; i < 32; ++i) {
#pragma unroll
        for (int off = 1; off < 16; off <<= 1)
            pa[i] += __shfl_xor(pa[i], off, 64);
    }
    // a_red aliases As (K-loop done; last barrier synchronized all reads)
    float (*a_red)[BM] = (float (*)[BM])&As[0][0][0];   // [4][256]
    if ((lane & 15) == 0) {
        int rg = lane >> 4;
#pragma unroll
        for (int m = 0; m < 8; ++m)
#pragma unroll
            for (int j = 0; j < 4; ++j)
                a_red[wc][wr * 128 + m * 16 + rg * 4 + j] = pa[m * 4 + j];
    }
    __syncthreads();
    if (tid < BM) {
        float av = a_red[0][tid] + a_red[1][tid] + a_red[2][tid] + a_red[3][tid] + ba[0];
        a_out[row0 + tid] = av;
    }
}

// ---------------------------------------------------------------------------
// Merged softmax: per-bag max + sumexp + write normalized probs p[n]
// (p = 0 beyond len). 8 blocks x 1024 threads.
// ---------------------------------------------------------------------------
__global__ __launch_bounds__(1024)
void stats_kernel(const float* __restrict__ a, const int* __restrict__ lengths,
                  float* __restrict__ p)
{
    __shared__ float red[16];
    __shared__ float bcast;
    const int b = blockIdx.x, tid = threadIdx.x;
    const int wid = tid >> 6, lane = tid & 63;
    const int len = lengths[b];
    const float* ab = a + (size_t)b * NN;

    float v[8];
    bool valid[8];
    float m = -3e38f;
#pragma unroll
    for (int i = 0; i < 8; ++i) {
        int n = tid + i * 1024;
        valid[i] = n < len;
        v[i] = valid[i] ? ab[n] : -3e38f;
        m = fmaxf(m, v[i]);
    }
    m = wave_reduce_max(m);
    if (lane == 0) red[wid] = m;
    __syncthreads();
    if (tid < 64) {
        float mm = (lane < 16) ? red[lane] : -3e38f;
        mm = wave_reduce_max(mm);
        if (lane == 0) bcast = mm;
    }
    __syncthreads();
    m = bcast;

    float e[8];
    float s = 0.f;
#pragma unroll
    for (int i = 0; i < 8; ++i) {
        e[i] = valid[i] ? expf(v[i] - m) : 0.f;
        s += e[i];
    }
    s = wave_reduce_sum(s);
    __syncthreads();
    if (lane == 0) red[wid] = s;
    __syncthreads();
    if (tid < 64) {
        float ss = (lane < 16) ? red[lane] : 0.f;
        ss = wave_reduce_sum(ss);
        if (lane == 0) bcast = ss;
    }
    __syncthreads();
    const float inv = 1.f / bcast;
#pragma unroll
    for (int i = 0; i < 8; ++i)
        p[(size_t)b * NN + tid + i * 1024] = e[i] * inv;
}

// ---------------------------------------------------------------------------
// pool: grid (32, NB) x 256 thr. thread: sub = tid>>6 (row phase),
// cg = tid&63 (4 cols). 64 rows/thread, in-block reduce over sub.
// ---------------------------------------------------------------------------
__global__ __launch_bounds__(256)
void pool_kernel(const unsigned short* __restrict__ h, const float* __restrict__ p,
                 float* __restrict__ part)
{
    __shared__ float pr[4][NH];
    const int b = blockIdx.y;
    const int s = blockIdx.x;
    const int sub = threadIdx.x >> 6;
    const int cg  = threadIdx.x & 63;
    const int n0  = s * 256 + sub;

    const unsigned short* hb = h + ((size_t)b * NN + n0) * NH + cg * 4;
    const float* pb = p + (size_t)b * NN + n0;

    float ax = 0.f, ay = 0.f, az = 0.f, aw = 0.f;
#pragma unroll 8
    for (int i = 0; i < 64; ++i) {
        float pv = pb[i * 4];
        ushort4 hv = *(const ushort4*)(hb + (size_t)i * 4 * NH);
        ax = fmaf(pv, bf2f(hv.x), ax);
        ay = fmaf(pv, bf2f(hv.y), ay);
        az = fmaf(pv, bf2f(hv.z), az);
        aw = fmaf(pv, bf2f(hv.w), aw);
    }
    pr[sub][cg * 4 + 0] = ax;
    pr[sub][cg * 4 + 1] = ay;
    pr[sub][cg * 4 + 2] = az;
    pr[sub][cg * 4 + 3] = aw;
    __syncthreads();
    int c = threadIdx.x;
    part[((size_t)b * 32 + s) * NH + c] = pr[0][c] + pr[1][c] + pr[2][c] + pr[3][c];
}

// ---------------------------------------------------------------------------
// final: one block per bag. pooled = sum of 32 partials; logits = pooled@Wc+bc
// ---------------------------------------------------------------------------
__global__ void final_kernel(const float* __restrict__ part, const float* __restrict__ Wc,
                             const float* __restrict__ bc, float* __restrict__ out)
{
    __shared__ float red0[4], red1[4];
    const int b = blockIdx.x;
    const int c = threadIdx.x;
    const float wc0 = Wc[c * NC + 0], wc1 = Wc[c * NC + 1];
    const int wave = threadIdx.x >> 6, lane = threadIdx.x & 63;

    float pooled = 0.f;
#pragma unroll 8
    for (int s = 0; s < 32; ++s)
        pooled += part[((size_t)b * 32 + s) * NH + c];
    float l0 = wave_reduce_sum(pooled * wc0);
    float l1 = wave_reduce_sum(pooled * wc1);
    if (lane == 0) { red0[wave] = l0; red1[wave] = l1; }
    __syncthreads();
    if (threadIdx.x == 0) {
        out[b * NC + 0] = red0[0] + red0[1] + red0[2] + red0[3] + bc[0];
        out[b * NC + 1] = red1[0] + red1[1] + red1[2] + red1[3] + bc[1];
    }
}

extern "C" void kernel_launch(void* const* d_in, const int* in_sizes, int n_in,
                              void* d_out, int out_size, void* d_ws, size_t ws_size,
                              hipStream_t stream)
{
    const float* x       = (const float*)d_in[0];
    const int*   lengths = (const int*)d_in[1];
    const float* Wp      = (const float*)d_in[2];
    const float* bp      = (const float*)d_in[3];
    const float* Wa      = (const float*)d_in[4];
    const float* ba      = (const float*)d_in[5];
    const float* Wc      = (const float*)d_in[6];
    const float* bc      = (const float*)d_in[7];
    float* out = (float*)d_out;

    // workspace layout
    unsigned short* whi   = (unsigned short*)d_ws;            // 512 KB
    unsigned short* wlo   = whi + 262144;                     // 512 KB
    unsigned short* h_buf = wlo + 262144;                     // 32 MB bf16
    float*  a_buf  = (float*)(h_buf + (size_t)M_ALL * NH);    // 256 KB
    float*  p_buf  = a_buf + M_ALL;                           // 256 KB
    float*  part   = p_buf + M_ALL;                           // 8*32*256 f = 256 KB

    pack_kernel<<<128, 256, 0, stream>>>(Wp, whi, wlo);
    gemm_kernel<<<M_ALL / BM, 512, 0, stream>>>(x, whi, wlo, bp, Wa, ba, h_buf, a_buf);
    stats_kernel<<<NB, 1024, 0, stream>>>(a_buf, lengths, p_buf);
    pool_kernel<<<dim3(32, NB), 256, 0, stream>>>(h_buf, p_buf, part);
    final_kernel<<<NB, 256, 0, stream>>>(part, Wc, bc, out);
}

// Round 7
// 117.636 us; speedup vs baseline: 1.3644x; 1.1801x over previous
//
#include <hip/hip_runtime.h>
#include <hip/hip_bf16.h>
#include <math.h>

#define NB 8
#define NN 8192
#define ND 1024
#define NH 256
#define NC 2
#define M_ALL (NB * NN)   // 65536 rows
#define BM 256            // block tile rows
#define BK 32             // K per iteration
#define NT (ND / BK)      // 32 iterations

typedef __attribute__((ext_vector_type(8))) short bf16x8;
typedef __attribute__((ext_vector_type(4))) float f32x4;

// barrier WITHOUT the compiler's vmcnt(0) drain: LDS ordering only.
#define BARRIER_LGKM() asm volatile("s_waitcnt lgkmcnt(0)\n\ts_barrier" ::: "memory")

__device__ inline unsigned short f2bf(float f) {   // RNE float -> bf16 bits
    unsigned int u = __builtin_bit_cast(unsigned int, f);
    u += 0x7FFFu + ((u >> 16) & 1u);
    return (unsigned short)(u >> 16);
}
__device__ inline float bf2f(unsigned short s) {
    unsigned int u = ((unsigned int)s) << 16;
    return __builtin_bit_cast(float, u);
}
__device__ inline unsigned int pk_bf16(float a, float b) {  // low=a, high=b (v_cvt_pk path)
    __hip_bfloat162 t = __float22bfloat162_rn(float2{a, b});
    unsigned int r;
    __builtin_memcpy(&r, &t, 4);
    return r;
}

__device__ inline float wave_reduce_sum(float v) {
#pragma unroll
    for (int off = 32; off > 0; off >>= 1) v += __shfl_down(v, off, 64);
    return v;
}
__device__ inline float wave_reduce_max(float v) {
#pragma unroll
    for (int off = 32; off > 0; off >>= 1) v = fmaxf(v, __shfl_down(v, off, 64));
    return v;
}

// ---------------------------------------------------------------------------
// Pack Wp into bf16 hi/lo, MFMA-B-fragment-contiguous:
// frag (t = kstep 0..31, f = col-frag 0..15), lane l holds
// B[k = t*32 + (l>>4)*8 + j][col = f*16 + (l&15)], j=0..7 contiguous.
// ---------------------------------------------------------------------------
__global__ void pack_kernel(const float* __restrict__ Wp,
                            unsigned short* __restrict__ hi,
                            unsigned short* __restrict__ lo)
{
    int idx  = blockIdx.x * 256 + threadIdx.x;   // 0..32767
    int lane = idx & 63;
    int f    = (idx >> 6) & 15;
    int t    = idx >> 10;
    int col  = f * 16 + (lane & 15);
    int k0   = t * 32 + (lane >> 4) * 8;
    size_t off = (size_t)idx * 8;
#pragma unroll
    for (int j = 0; j < 8; ++j) {
        float w = Wp[(size_t)(k0 + j) * NH + col];
        unsigned short h = f2bf(w);
        hi[off + j] = h;
        lo[off + j] = f2bf(w - bf2f(h));
    }
}

// ---------------------------------------------------------------------------
// GEMM: h = silu(x @ Wp + bp) stored bf16; fused a = h @ Wa + ba.
// 256x256 tile, 8 waves (2 row x 4 col groups), BK=32, 32 iters.
// vmcnt-FIFO-aware order per iter: [B loads (L2)] -> [x prefetch t+3]
// -> MFMA (B wait = vmcnt(4), x survives) -> dswrite(x t+1) -> lgkm barrier.
// x depth-3 (3 rotating reg sets). Early-exit for blocks beyond bag length.
// Epilogue re-layouts h through LDS for coalesced 1KB global stores.
// ---------------------------------------------------------------------------
__global__ __launch_bounds__(512, 2)
void gemm_kernel(const float* __restrict__ x,
                 const unsigned short* __restrict__ Bhi,
                 const unsigned short* __restrict__ Blo,
                 const float* __restrict__ bp,
                 const float* __restrict__ Wa,
                 const float* __restrict__ ba,
                 const int* __restrict__ lengths,
                 unsigned short* __restrict__ h_out,
                 float* __restrict__ a_out)
{
    __shared__ __align__(16) unsigned char lds_raw[32768];  // As dbuf 2x16KB; reused as h pass buffer
    __shared__ float a_red[4][BM];

    const int tid  = threadIdx.x;
    const int wave = tid >> 6;
    const int lane = tid & 63;
    const int wr = wave >> 2;           // 0..1: 128-row group
    const int wc = wave & 3;            // 0..3: 64-col group
    const int blk = blockIdx.x;
    const size_t row0 = (size_t)blk * BM;

    // ragged early-exit: this block's rows all beyond bag length
    const int bag   = blk >> 5;                // 32 blocks per bag
    const int lrow0 = (blk & 31) * BM;
    const int len   = lengths[bag];
    if (lrow0 >= len) return;

    // ---- staging geometry: thread -> 2 chunks of 8 floats (rows r0l, r0l+128)
    const int r0l = tid >> 2;                  // 0..127
    const int sl  = tid & 3;                   // chunk-in-row
    const float* xp0 = x + (row0 + r0l) * ND + sl * 8;
    const float* xp1 = xp0 + (size_t)128 * ND;
    const int offA = (((sl + (r0l >> 1)) & 3) << 4);   // rotated 16B slot (same for row+128)
    char* const wb0 = (char*)lds_raw + r0l * 64 + offA;

    struct XR { float4 a0, b0, a1, b1; };
    XR gx0, gx1, gx2;
    auto issueX = [&](int t, XR& r) {
        const float4* p0 = (const float4*)(xp0 + (size_t)t * BK);
        const float4* p1 = (const float4*)(xp1 + (size_t)t * BK);
        r.a0 = p0[0]; r.b0 = p0[1];
        r.a1 = p1[0]; r.b1 = p1[1];
    };
    auto dswrite = [&](int buf, const XR& r) {
        uint4 w0, w1;
        w0.x = pk_bf16(r.a0.x, r.a0.y); w0.y = pk_bf16(r.a0.z, r.a0.w);
        w0.z = pk_bf16(r.b0.x, r.b0.y); w0.w = pk_bf16(r.b0.z, r.b0.w);
        w1.x = pk_bf16(r.a1.x, r.a1.y); w1.y = pk_bf16(r.a1.z, r.a1.w);
        w1.z = pk_bf16(r.b1.x, r.b1.y); w1.w = pk_bf16(r.b1.z, r.b1.w);
        char* base = wb0 + buf * 16384;
        *(uint4*)base = w0;
        *(uint4*)(base + 8192) = w1;           // row + 128
    };

    // ---- B fragment bases (frag idx = kstep*16 + wc*4 + n; 512 ushorts/frag)
    const unsigned short* bhp = Bhi + ((size_t)(wc * 4) * 64 + lane) * 8;
    const unsigned short* blp = Blo + ((size_t)(wc * 4) * 64 + lane) * 8;

    // ---- A fragment addressing (const per thread except m)
    const int aoff = ((((lane >> 4) + ((lane & 15) >> 1)) & 3) << 4);
    const int arow_base = wr * 128 + (lane & 15);

    f32x4 acc[8][4];
#pragma unroll
    for (int m = 0; m < 8; ++m)
#pragma unroll
        for (int n = 0; n < 4; ++n) acc[m][n] = f32x4{0.f, 0.f, 0.f, 0.f};

    auto body = [&](int t, XR& cons, XR& iss) {
        // 1) B loads FIRST (so their wait leaves younger x loads in flight)
        const unsigned short* bhB = bhp + (size_t)t * 8192;
        const unsigned short* blB = blp + (size_t)t * 8192;
        bf16x8 bh[4], bl[4];
#pragma unroll
        for (int n = 0; n < 4; ++n) {
            bh[n] = *(const bf16x8*)(bhB + n * 512);
            bl[n] = *(const bf16x8*)(blB + n * 512);
        }
        // 2) x prefetch (newest vmem -> survives the B wait)
        if (t + 3 < NT) issueX(t + 3, iss);
        // 3) A frags + MFMA (hi block then lo block per 4-m half)
        const char* ab = (const char*)lds_raw + (t & 1) * 16384;
        __builtin_amdgcn_s_setprio(1);
#pragma unroll
        for (int mm = 0; mm < 2; ++mm) {
            bf16x8 af[4];
#pragma unroll
            for (int q = 0; q < 4; ++q)
                af[q] = *(const bf16x8*)(ab + (arow_base + (mm * 4 + q) * 16) * 64 + aoff);
#pragma unroll
            for (int n = 0; n < 4; ++n)
#pragma unroll
                for (int q = 0; q < 4; ++q)
                    acc[mm * 4 + q][n] = __builtin_amdgcn_mfma_f32_16x16x32_bf16(af[q], bh[n], acc[mm * 4 + q][n], 0, 0, 0);
#pragma unroll
            for (int n = 0; n < 4; ++n)
#pragma unroll
                for (int q = 0; q < 4; ++q)
                    acc[mm * 4 + q][n] = __builtin_amdgcn_mfma_f32_16x16x32_bf16(af[q], bl[n], acc[mm * 4 + q][n], 0, 0, 0);
        }
        __builtin_amdgcn_s_setprio(0);
        // 4) stage tile t+1 into other buffer (its loads drained at B wait)
        if (t < NT - 1) dswrite((t + 1) & 1, cons);
        BARRIER_LGKM();
    };

    // prologue: tile tau -> reg set tau%3; tile0 -> buf0
    issueX(0, gx0);
    issueX(1, gx1);
    dswrite(0, gx0);
    issueX(2, gx2);
    BARRIER_LGKM();

    // iter t: consumes set (t+1)%3, issues tile t+3 into set t%3
    for (int tt = 0; tt < 30; tt += 3) {
        body(tt,     gx1, gx0);
        body(tt + 1, gx2, gx1);
        body(tt + 2, gx0, gx2);
    }
    body(30, gx1, gx0);
    body(31, gx2, gx1);

    // ---- epilogue: bias + SiLU; h via LDS re-layout (coalesced stores); fused a
    float pa[32];
#pragma unroll
    for (int i = 0; i < 32; ++i) pa[i] = 0.f;

    const int rg = lane >> 4;
    float bpc[4], wac[4];
#pragma unroll
    for (int n = 0; n < 4; ++n) {
        int col = wc * 64 + n * 16 + (lane & 15);
        bpc[n] = bp[col];
        wac[n] = Wa[col];
    }

#pragma unroll
    for (int p = 0; p < 4; ++p) {              // 4 passes of 64 rows through lds_raw
        if (wr == (p >> 1)) {
#pragma unroll
            for (int q = 0; q < 4; ++q) {
                const int m = (p & 1) * 4 + q;
#pragma unroll
                for (int n = 0; n < 4; ++n) {
                    const int col = wc * 64 + n * 16 + (lane & 15);
#pragma unroll
                    for (int j = 0; j < 4; ++j) {
                        float v  = acc[m][n][j] + bpc[n];
                        float hh = v / (1.f + __expf(-v));
                        pa[m * 4 + j] = fmaf(hh, wac[n], pa[m * 4 + j]);
                        const int rl = q * 16 + rg * 4 + j;       // row within pass
                        const int byte = rl * 512 + ((col * 2) ^ (((rl >> 2) & 7) << 5));
                        *(unsigned short*)((char*)lds_raw + byte) = f2bf(hh);
                    }
                }
            }
        }
        __syncthreads();
        // coalesced copy: 64 rows x 512 B
#pragma unroll
        for (int w = 0; w < 4; ++w) {
            const int idx = w * 512 + tid;
            const int rl = idx >> 5, ch = idx & 31;
            const int lbyte = rl * 512 + ((ch * 16) ^ (((rl >> 2) & 7) << 5));
            uint4 vv = *(const uint4*)((const char*)lds_raw + lbyte);
            *(uint4*)((char*)h_out + (row0 + p * 64 + rl) * 512 + ch * 16) = vv;
        }
        __syncthreads();
    }

    // attention logits: reduce pa over the 16 lanes sharing each row
#pragma unroll
    for (int i = 0; i < 32; ++i) {
#pragma unroll
        for (int off = 1; off < 16; off <<= 1)
            pa[i] += __shfl_xor(pa[i], off, 64);
    }
    if ((lane & 15) == 0) {
#pragma unroll
        for (int m = 0; m < 8; ++m)
#pragma unroll
            for (int j = 0; j < 4; ++j)
                a_red[wc][wr * 128 + m * 16 + rg * 4 + j] = pa[m * 4 + j];
    }
    __syncthreads();
    if (tid < BM) {
        float av = a_red[0][tid] + a_red[1][tid] + a_red[2][tid] + a_red[3][tid] + ba[0];
        a_out[row0 + tid] = av;
    }
}

// ---------------------------------------------------------------------------
// Merged softmax: per-bag max + sumexp + write normalized probs p[n]
// (p = 0 beyond len). 8 blocks x 1024 threads.
// ---------------------------------------------------------------------------
__global__ __launch_bounds__(1024)
void stats_kernel(const float* __restrict__ a, const int* __restrict__ lengths,
                  float* __restrict__ p)
{
    __shared__ float red[16];
    __shared__ float bcast;
    const int b = blockIdx.x, tid = threadIdx.x;
    const int wid = tid >> 6, lane = tid & 63;
    const int len = lengths[b];
    const float* ab = a + (size_t)b * NN;

    float v[8];
    bool valid[8];
    float m = -3e38f;
#pragma unroll
    for (int i = 0; i < 8; ++i) {
        int n = tid + i * 1024;
        valid[i] = n < len;
        v[i] = valid[i] ? ab[n] : -3e38f;
        m = fmaxf(m, v[i]);
    }
    m = wave_reduce_max(m);
    if (lane == 0) red[wid] = m;
    __syncthreads();
    if (tid < 64) {
        float mm = (lane < 16) ? red[lane] : -3e38f;
        mm = wave_reduce_max(mm);
        if (lane == 0) bcast = mm;
    }
    __syncthreads();
    m = bcast;

    float e[8];
    float s = 0.f;
#pragma unroll
    for (int i = 0; i < 8; ++i) {
        e[i] = valid[i] ? expf(v[i] - m) : 0.f;
        s += e[i];
    }
    s = wave_reduce_sum(s);
    __syncthreads();
    if (lane == 0) red[wid] = s;
    __syncthreads();
    if (tid < 64) {
        float ss = (lane < 16) ? red[lane] : 0.f;
        ss = wave_reduce_sum(ss);
        if (lane == 0) bcast = ss;
    }
    __syncthreads();
    const float inv = 1.f / bcast;
#pragma unroll
    for (int i = 0; i < 8; ++i)
        p[(size_t)b * NN + tid + i * 1024] = e[i] * inv;
}

// ---------------------------------------------------------------------------
// pool: grid (32, NB) x 256 thr. Early-skip slices beyond bag length.
// ---------------------------------------------------------------------------
__global__ __launch_bounds__(256)
void pool_kernel(const unsigned short* __restrict__ h, const float* __restrict__ p,
                 const int* __restrict__ lengths, float* __restrict__ part)
{
    __shared__ float pr[4][NH];
    const int b = blockIdx.y;
    const int s = blockIdx.x;
    const int len = lengths[b];
    if (s * 256 >= len) {
        part[((size_t)b * 32 + s) * NH + threadIdx.x] = 0.f;
        return;
    }
    const int sub = threadIdx.x >> 6;
    const int cg  = threadIdx.x & 63;
    const int n0  = s * 256 + sub;

    const unsigned short* hb = h + ((size_t)b * NN + n0) * NH + cg * 4;
    const float* pb = p + (size_t)b * NN + n0;

    float ax = 0.f, ay = 0.f, az = 0.f, aw = 0.f;
#pragma unroll 8
    for (int i = 0; i < 64; ++i) {
        float pv = pb[i * 4];
        ushort4 hv = *(const ushort4*)(hb + (size_t)i * 4 * NH);
        ax = fmaf(pv, bf2f(hv.x), ax);
        ay = fmaf(pv, bf2f(hv.y), ay);
        az = fmaf(pv, bf2f(hv.z), az);
        aw = fmaf(pv, bf2f(hv.w), aw);
    }
    pr[sub][cg * 4 + 0] = ax;
    pr[sub][cg * 4 + 1] = ay;
    pr[sub][cg * 4 + 2] = az;
    pr[sub][cg * 4 + 3] = aw;
    __syncthreads();
    int c = threadIdx.x;
    part[((size_t)b * 32 + s) * NH + c] = pr[0][c] + pr[1][c] + pr[2][c] + pr[3][c];
}

// ---------------------------------------------------------------------------
// final: one block per bag. pooled = sum of 32 partials; logits = pooled@Wc+bc
// ---------------------------------------------------------------------------
__global__ void final_kernel(const float* __restrict__ part, const float* __restrict__ Wc,
                             const float* __restrict__ bc, float* __restrict__ out)
{
    __shared__ float red0[4], red1[4];
    const int b = blockIdx.x;
    const int c = threadIdx.x;
    const float wc0 = Wc[c * NC + 0], wc1 = Wc[c * NC + 1];
    const int wave = threadIdx.x >> 6, lane = threadIdx.x & 63;

    float pooled = 0.f;
#pragma unroll 8
    for (int s = 0; s < 32; ++s)
        pooled += part[((size_t)b * 32 + s) * NH + c];
    float l0 = wave_reduce_sum(pooled * wc0);
    float l1 = wave_reduce_sum(pooled * wc1);
    if (lane == 0) { red0[wave] = l0; red1[wave] = l1; }
    __syncthreads();
    if (threadIdx.x == 0) {
        out[b * NC + 0] = red0[0] + red0[1] + red0[2] + red0[3] + bc[0];
        out[b * NC + 1] = red1[0] + red1[1] + red1[2] + red1[3] + bc[1];
    }
}

extern "C" void kernel_launch(void* const* d_in, const int* in_sizes, int n_in,
                              void* d_out, int out_size, void* d_ws, size_t ws_size,
                              hipStream_t stream)
{
    const float* x       = (const float*)d_in[0];
    const int*   lengths = (const int*)d_in[1];
    const float* Wp      = (const float*)d_in[2];
    const float* bp      = (const float*)d_in[3];
    const float* Wa      = (const float*)d_in[4];
    const float* ba      = (const float*)d_in[5];
    const float* Wc      = (const float*)d_in[6];
    const float* bc      = (const float*)d_in[7];
    float* out = (float*)d_out;

    // workspace layout
    unsigned short* whi   = (unsigned short*)d_ws;            // 512 KB
    unsigned short* wlo   = whi + 262144;                     // 512 KB
    unsigned short* h_buf = wlo + 262144;                     // 32 MB bf16
    float*  a_buf  = (float*)(h_buf + (size_t)M_ALL * NH);    // 256 KB
    float*  p_buf  = a_buf + M_ALL;                           // 256 KB
    float*  part   = p_buf + M_ALL;                           // 256 KB

    pack_kernel<<<128, 256, 0, stream>>>(Wp, whi, wlo);
    gemm_kernel<<<M_ALL / BM, 512, 0, stream>>>(x, whi, wlo, bp, Wa, ba, lengths, h_buf, a_buf);
    stats_kernel<<<NB, 1024, 0, stream>>>(a_buf, lengths, p_buf);
    pool_kernel<<<dim3(32, NB), 256, 0, stream>>>(h_buf, p_buf, lengths, part);
    final_kernel<<<NB, 256, 0, stream>>>(part, Wc, bc, out);
}